// Round 8
// baseline (249.752 us; speedup 1.0000x reference)
//
#include <hip/hip_runtime.h>
#include <hip/hip_bf16.h>
#include <cstdint>

#define D_MODEL 1024
#define NHEADS 16
#define HDIM 64
#define SEQ 2048
#define NBATCH 2
#define BT (NBATCH * SEQ) /* 4096 */

typedef short bf16x8 __attribute__((ext_vector_type(8)));
typedef float f32x4 __attribute__((ext_vector_type(4)));
typedef unsigned short u16;
typedef unsigned int u32;

__device__ inline u16 f2bf(float f) {  // RNE
    union { float f; u32 u; } x;
    x.f = f;
    u32 r = (x.u + 0x7fffu + ((x.u >> 16) & 1u)) >> 16;
    return (u16)r;
}

__device__ inline u32 pack2bf(float a, float b) {  // lo=bf16(a), hi=bf16(b), RNE via HW pack
    union { __hip_bfloat162 h; u32 u; } c;
    c.h = __float22bfloat162_rn(float2{a, b});
    return c.u;
}

__device__ inline float bf2f(u16 v) {
    union { u32 u; float f; } x;
    x.u = ((u32)v) << 16;
    return x.f;
}

__device__ inline void async_copy16(const u16* g, u16* l) {
    __builtin_amdgcn_global_load_lds((const __attribute__((address_space(1))) void*)g,
                                     (__attribute__((address_space(3))) void*)l, 16, 0, 0);
}

// ---------------- prep: casts + rope tables, one launch ----------------
#define X4 (BT * D_MODEL / 4)        /* 1048576 = 2^20 */
#define W4 (D_MODEL * D_MODEL / 4)   /* 262144  = 2^18 */
#define ROPE_N (SEQ * 32)            /* 65536 */

__global__ void prep_kernel(const float* __restrict__ x,
                            const float* __restrict__ wq, const float* __restrict__ wk,
                            const float* __restrict__ wv, const float* __restrict__ wo,
                            u16* __restrict__ xb,
                            u16* __restrict__ dq, u16* __restrict__ dk,
                            u16* __restrict__ dv, u16* __restrict__ dow,
                            float* __restrict__ cosT, float* __restrict__ sinT) {
    int idx = blockIdx.x * blockDim.x + threadIdx.x;
    if (idx < X4) {
        float4 v = ((const float4*)x)[idx];
        ushort4 o;
        o.x = f2bf(v.x); o.y = f2bf(v.y); o.z = f2bf(v.z); o.w = f2bf(v.w);
        ((ushort4*)xb)[idx] = o;
    } else if (idx < X4 + 4 * W4) {
        int j = idx - X4;
        int w = j >> 18, i = j & (W4 - 1);
        const float* s = (w == 0) ? wq : (w == 1) ? wk : (w == 2) ? wv : wo;
        u16* d = (w == 0) ? dq : (w == 1) ? dk : (w == 2) ? dv : dow;
        float4 v = ((const float4*)s)[i];
        ushort4 o;
        o.x = f2bf(v.x); o.y = f2bf(v.y); o.z = f2bf(v.z); o.w = f2bf(v.w);
        ((ushort4*)d)[i] = o;
    } else {
        int j = idx - (X4 + 4 * W4);
        if (j < ROPE_N) {
            int t = j >> 5, dd = j & 31;
            float invf = exp2f(-(float)dd * (13.287712379549449f / 32.0f));
            float ang = (float)t * invf;
            float s, c;
            sincosf(ang, &s, &c);
            cosT[t * HDIM + dd] = c;      cosT[t * HDIM + dd + 32] = c;
            sinT[t * HDIM + dd] = s;      sinT[t * HDIM + dd + 32] = s;
        }
    }
}

// ---------------- m97-style GEMM core (128x128 tile) ----------------
__device__ inline void gemm_tile_core(const u16* __restrict__ A, const u16* __restrict__ Bw,
                                      int blkM, int blkN,
                                      u16* Asmem, u16* Bsmem, f32x4 acc[4][4]) {
    const int tid = threadIdx.x;
    const int lane = tid & 63;
    const int wave = tid >> 6;
    const int waveM = wave >> 1, waveN = wave & 1;
    const int quad = lane >> 4, l16 = lane & 15;

    const int srow = tid >> 2;
    const int scol = (tid & 3) << 3;
    const u16* Ag0 = A + (size_t)(blkM * 128 + srow) * D_MODEL + scol;
    const u16* Ag1 = Ag0 + (size_t)64 * D_MODEL;
    const u16* Bg0 = Bw + (size_t)(blkN * 128 + srow) * D_MODEL + scol;
    const u16* Bg1 = Bg0 + (size_t)64 * D_MODEL;
    u16* Al0 = Asmem + srow * 32 + scol;
    u16* Al1 = Al0 + 64 * 32;
    u16* Bl0 = Bsmem + srow * 32 + scol;
    u16* Bl1 = Bl0 + 64 * 32;

    for (int k0 = 0; k0 < D_MODEL; k0 += 32) {
        __syncthreads();
        async_copy16(Ag0 + k0, Al0);
        async_copy16(Ag1 + k0, Al1);
        async_copy16(Bg0 + k0, Bl0);
        async_copy16(Bg1 + k0, Bl1);
        __syncthreads();
        bf16x8 af[4], bfr[4];
#pragma unroll
        for (int mt = 0; mt < 4; ++mt)
            af[mt] = *(const bf16x8*)&Asmem[(waveM * 64 + mt * 16 + l16) * 32 + quad * 8];
#pragma unroll
        for (int nt = 0; nt < 4; ++nt)
            bfr[nt] = *(const bf16x8*)&Bsmem[(waveN * 64 + nt * 16 + l16) * 32 + quad * 8];
#pragma unroll
        for (int mt = 0; mt < 4; ++mt)
#pragma unroll
            for (int nt = 0; nt < 4; ++nt)
                acc[mt][nt] = __builtin_amdgcn_mfma_f32_16x16x32_bf16(af[mt], bfr[nt], acc[mt][nt], 0, 0, 0);
    }
}

// ---------------- fused QKV projection + bias + RoPE + layout ----------------
#define QSCALE 0.1803368801111204f /* (1/8) * log2(e) */
#define VPAD 132 /* vtile row stride in u16 */

__global__ __launch_bounds__(256) void gemm_qkv_kernel(
    const u16* __restrict__ xb,
    const u16* __restrict__ wqb, const u16* __restrict__ wkb, const u16* __restrict__ wvb,
    const float* __restrict__ bq, const float* __restrict__ bk, const float* __restrict__ bv,
    const float* __restrict__ cosT, const float* __restrict__ sinT,
    u16* __restrict__ Qb, u16* __restrict__ Kb, u16* __restrict__ VTb) {
    // union: [Asmem 128x32 | Bsmem 128x32] for the K-loop, vtile 128xVPAD for the V epilogue
    __shared__ __align__(16) u16 smem[128 * VPAD];
    u16* Asmem = smem;
    u16* Bsmem = smem + 128 * 32;

    const int z = blockIdx.z;
    const u16* Bw = (z == 0) ? wqb : (z == 1) ? wkb : wvb;
    const float* bias = (z == 0) ? bq : (z == 1) ? bk : bv;

    f32x4 acc[4][4];
#pragma unroll
    for (int mt = 0; mt < 4; ++mt)
#pragma unroll
        for (int nt = 0; nt < 4; ++nt)
            acc[mt][nt] = (f32x4){0.f, 0.f, 0.f, 0.f};

    gemm_tile_core(xb, Bw, blockIdx.x, blockIdx.y, Asmem, Bsmem, acc);

    const int tid = threadIdx.x;
    const int lane = tid & 63, wave = tid >> 6;
    const int waveM = wave >> 1, waveN = wave & 1;
    const int quad = lane >> 4, l16 = lane & 15;
    const int gm0 = blockIdx.x * 128 + waveM * 64 + quad * 4;
    const int gn0 = blockIdx.y * 128 + waveN * 64 + l16;

    float bvv[4];
#pragma unroll
    for (int nt = 0; nt < 4; ++nt) bvv[nt] = bias[gn0 + nt * 16];
#pragma unroll
    for (int mt = 0; mt < 4; ++mt)
#pragma unroll
        for (int nt = 0; nt < 4; ++nt)
#pragma unroll
            for (int r = 0; r < 4; ++r) acc[mt][nt][r] += bvv[nt];

    if (z < 2) {
        u16* dst = (z == 0) ? Qb : Kb;
        const float post = (z == 0) ? QSCALE : 1.0f;
#pragma unroll
        for (int mt = 0; mt < 4; ++mt) {
#pragma unroll
            for (int nt = 0; nt < 4; ++nt) {
                int n = gn0 + nt * 16;
                int d = n & 63, h = n >> 6;
#pragma unroll
                for (int r = 0; r < 4; ++r) {
                    int gm = gm0 + mt * 16 + r;
                    int t = gm & (SEQ - 1), b = gm >> 11;
                    float c = cosT[t * HDIM + d], s = sinT[t * HDIM + d];
                    float part = acc[mt][nt ^ 2][r];
                    float rot = (d < 32) ? -part : part;
                    float val = (acc[mt][nt][r] * c + rot * s) * post;
                    dst[((b * NHEADS + h) * SEQ + t) * HDIM + d] = f2bf(val);
                }
            }
        }
    } else {
        // V epilogue: transpose through LDS, then fully-coalesced stores to VTb[bh][d][t]
        __syncthreads();  // all waves done reading Asmem/Bsmem
#pragma unroll
        for (int mt = 0; mt < 4; ++mt) {
            int t_local = waveM * 64 + mt * 16 + quad * 4;
#pragma unroll
            for (int nt = 0; nt < 4; ++nt) {
                int n_local = waveN * 64 + nt * 16 + l16;
                uint2 w;
                w.x = pack2bf(acc[mt][nt][0], acc[mt][nt][1]);
                w.y = pack2bf(acc[mt][nt][2], acc[mt][nt][3]);
                *(uint2*)&smem[n_local * VPAD + t_local] = w;
            }
        }
        __syncthreads();
        const int row = tid >> 1;             // n_local 0..127
        const int hc = (tid & 1) * 64;        // t half-chunk
        const int n_g = blockIdx.y * 128 + row;
        const int h = n_g >> 6, d = n_g & 63;
        const int b = (blockIdx.x * 128) >> 11;
        const int t0 = ((blockIdx.x * 128) & (SEQ - 1)) + hc;
        u16* dst = &VTb[((size_t)(b * NHEADS + h) * HDIM + d) * SEQ + t0];
        const u16* src = &smem[row * VPAD + hc];
#pragma unroll
        for (int j = 0; j < 8; ++j)
            *(int4*)&dst[j * 8] = *(const int4*)&src[j * 8];
    }
}

// ---------------- flash attention: BK=128 rounds, reg-dbuf staging, 64 q/wave, kt-split 2 ----
// grid: x = 8 (q tiles of 256), y = 32 (bh), z = 2 (kt halves). block = 256 = 4 waves, 64 q/wave.
// 8 barrier rounds of 128 kk (2 sub-tiles of 64); tile i+1 prefetched into VGPRs during compute.
#define LPAD 72   /* Ks/Ps row stride in u16 */
#define VSTR 136  /* VTs row stride in u16 */

__global__ __launch_bounds__(256, 2) void flash_kernel(
    const u16* __restrict__ Qb, const u16* __restrict__ Kb, const u16* __restrict__ VTb,
    u16* __restrict__ Po0, u16* __restrict__ Po1, float* __restrict__ Ls) {
    __shared__ __align__(16) u16 Ks[128 * LPAD];    // [kk 0..127][d]   18.4 KB
    __shared__ __align__(16) u16 VTs[64 * VSTR];    // [d][kk 0..127]   17.4 KB
    __shared__ __align__(16) u16 Ps[4][64 * LPAD];  // per-wave [q][kk] 36.9 KB

    const int tid = threadIdx.x;
    const int wave = tid >> 6, lane = tid & 63;
    const int quad = lane >> 4, l16 = lane & 15;
    const int bh = blockIdx.y;
    const int hf = blockIdx.z;
    const u16* Qh = Qb + (size_t)bh * SEQ * HDIM;
    const u16* Kh = Kb + (size_t)bh * SEQ * HDIM;
    const u16* Vh = VTb + (size_t)bh * HDIM * SEQ;
    const int qblk = blockIdx.x * 256 + wave * 64;
    u16* Pw = (u16*)Ps[wave];

    // Q B-frags (Q pre-scaled by 0.125*log2e): aq[nt2][ks], 64 q rows
    bf16x8 aq[4][2];
#pragma unroll
    for (int nt2 = 0; nt2 < 4; ++nt2)
#pragma unroll
        for (int ks = 0; ks < 2; ++ks)
            aq[nt2][ks] = *(const bf16x8*)&Qh[(qblk + nt2 * 16 + l16) * HDIM + ks * 32 + quad * 8];

    f32x4 o[4][4];
    float lsum[4] = {0.f, 0.f, 0.f, 0.f};
#pragma unroll
    for (int mt2 = 0; mt2 < 4; ++mt2)
#pragma unroll
        for (int nt = 0; nt < 4; ++nt) o[mt2][nt] = (f32x4){0.f, 0.f, 0.f, 0.f};

    // staging map: K 128x64 (lane: row tid>>1, 32-col half), V 64x128 (lane: row tid>>2, 32-col quarter)
    const int kr = tid >> 1, kc = (tid & 1) * 32;
    const int vr = tid >> 2, vc = (tid & 3) * 32;
    const u16* Kg = Kh + (size_t)kr * HDIM + kc;
    const u16* Vg = Vh + (size_t)vr * SEQ + vc;
    u16* Kl = Ks + kr * LPAD + kc;
    u16* Vl = VTs + vr * VSTR + vc;

    const int ktBase = hf * 8;
    int4 kreg[4], vreg[4];
    {
        const u16* kg = Kg + (size_t)(ktBase * 128) * HDIM;
        const u16* vg = Vg + ktBase * 128;
#pragma unroll
        for (int j = 0; j < 4; ++j) {
            kreg[j] = *(const int4*)(kg + 8 * j);
            vreg[j] = *(const int4*)(vg + 8 * j);
        }
    }

    for (int i = 0; i < 8; ++i) {
        __syncthreads();  // all waves done reading previous tile
#pragma unroll
        for (int j = 0; j < 4; ++j) {
            *(int4*)(Kl + 8 * j) = kreg[j];
            *(int4*)(Vl + 8 * j) = vreg[j];
        }
        __syncthreads();  // tile visible
        if (i < 7) {      // prefetch next tile into regs; latency hidden by compute below
            const u16* kg = Kg + (size_t)((ktBase + i + 1) * 128) * HDIM;
            const u16* vg = Vg + (ktBase + i + 1) * 128;
#pragma unroll
            for (int j = 0; j < 4; ++j) {
                kreg[j] = *(const int4*)(kg + 8 * j);
                vreg[j] = *(const int4*)(vg + 8 * j);
            }
        }

#pragma unroll
        for (int sub = 0; sub < 2; ++sub) {
            const u16* KsS = Ks + sub * 64 * LPAD;
            const int vOff = sub * 64;

            // S^T[kk][q] = K·Q^T : per wave 64kk x 64q. C/D: col(l16)=q, row(quad*4+r)=kk
            f32x4 sacc[4][4];
#pragma unroll
            for (int mt = 0; mt < 4; ++mt)
#pragma unroll
                for (int nt2 = 0; nt2 < 4; ++nt2) sacc[mt][nt2] = (f32x4){0.f, 0.f, 0.f, 0.f};
#pragma unroll
            for (int ks = 0; ks < 2; ++ks) {
                bf16x8 kf[4];
#pragma unroll
                for (int mt = 0; mt < 4; ++mt)
                    kf[mt] = *(const bf16x8*)&KsS[(mt * 16 + l16) * LPAD + ks * 32 + quad * 8];
#pragma unroll
                for (int mt = 0; mt < 4; ++mt)
#pragma unroll
                    for (int nt2 = 0; nt2 < 4; ++nt2)
                        sacc[mt][nt2] = __builtin_amdgcn_mfma_f32_16x16x32_bf16(kf[mt], aq[nt2][ks], sacc[mt][nt2], 0, 0, 0);
            }

            // P = exp2(S); lane holds 4 contiguous kk per (mt,nt2) -> b64 write; in-lane partial rowsum
#pragma unroll
            for (int mt = 0; mt < 4; ++mt) {
#pragma unroll
                for (int nt2 = 0; nt2 < 4; ++nt2) {
                    float p0 = __builtin_amdgcn_exp2f(sacc[mt][nt2][0]);
                    float p1 = __builtin_amdgcn_exp2f(sacc[mt][nt2][1]);
                    float p2 = __builtin_amdgcn_exp2f(sacc[mt][nt2][2]);
                    float p3 = __builtin_amdgcn_exp2f(sacc[mt][nt2][3]);
                    lsum[nt2] += (p0 + p1) + (p2 + p3);
                    uint2 w;
                    w.x = pack2bf(p0, p1);
                    w.y = pack2bf(p2, p3);
                    *(uint2*)&Pw[(nt2 * 16 + l16) * LPAD + mt * 16 + quad * 4] = w;
                }
            }
            // no barrier: Ps slice is private to this wave; DS ops are wave-ordered

            // O += P·V : A=P[q][kk] frags, B=V[d][kk] frags
#pragma unroll
            for (int ks = 0; ks < 2; ++ks) {
                bf16x8 pf[4], vf[4];
#pragma unroll
                for (int mt2 = 0; mt2 < 4; ++mt2)
                    pf[mt2] = *(const bf16x8*)&Pw[(mt2 * 16 + l16) * LPAD + ks * 32 + quad * 8];
#pragma unroll
                for (int nt = 0; nt < 4; ++nt)
                    vf[nt] = *(const bf16x8*)&VTs[(nt * 16 + l16) * VSTR + vOff + ks * 32 + quad * 8];
#pragma unroll
                for (int mt2 = 0; mt2 < 4; ++mt2)
#pragma unroll
                    for (int nt = 0; nt < 4; ++nt)
                        o[mt2][nt] = __builtin_amdgcn_mfma_f32_16x16x32_bf16(pf[mt2], vf[nt], o[mt2][nt], 0, 0, 0);
            }
        }
    }

    // complete row sums over the 4 quads (disjoint kk): lane l16 then holds q = nt2*16+l16
#pragma unroll
    for (int nt2 = 0; nt2 < 4; ++nt2) {
        lsum[nt2] += __shfl_xor(lsum[nt2], 16, 64);
        lsum[nt2] += __shfl_xor(lsum[nt2], 32, 64);
    }

    // epilogue: write UNNORMALIZED partial O (bf16) + row sums; gemm_out normalizes.
    const int b = bh >> 4, h = bh & 15;
    u16* dst = hf ? Po1 : Po0;
#pragma unroll
    for (int mt2 = 0; mt2 < 4; ++mt2) {
#pragma unroll
        for (int nt = 0; nt < 4; ++nt) {
            int d = nt * 16 + l16;
#pragma unroll
            for (int r = 0; r < 4; ++r) {
                int q = qblk + mt2 * 16 + quad * 4 + r;
                dst[((size_t)(b * SEQ + q)) * D_MODEL + h * HDIM + d] = f2bf(o[mt2][nt][r]);
            }
        }
    }
    if (quad == 0) {
#pragma unroll
        for (int nt2 = 0; nt2 < 4; ++nt2) {
            int q = qblk + nt2 * 16 + l16;
            Ls[hf * (32 * SEQ) + bh * SEQ + q] = lsum[nt2];
        }
    }
}

// ---------------- output projection: fused combine ((Po0+Po1)*rinv) in A-staging ----------
__global__ __launch_bounds__(256) void gemm_out_kernel(
    const u16* __restrict__ Po0, const u16* __restrict__ Po1, const float* __restrict__ Ls,
    const u16* __restrict__ wob, const float* __restrict__ bo, float* __restrict__ dout) {
    __shared__ __align__(16) u16 Asmem[64 * 32];
    __shared__ __align__(16) u16 Bsmem[128 * 32];

    const int tid = threadIdx.x;
    const int lane = tid & 63, wave = tid >> 6;
    const int waveM = wave >> 1, waveN = wave & 1;
    const int quad = lane >> 4, l16 = lane & 15;

    f32x4 acc[2][4];
#pragma unroll
    for (int mt = 0; mt < 2; ++mt)
#pragma unroll
        for (int nt = 0; nt < 4; ++nt) acc[mt][nt] = (f32x4){0.f, 0.f, 0.f, 0.f};

    const int srow = tid >> 2;
    const int scol = (tid & 3) << 3;
    const int q = blockIdx.x * 64 + srow;
    const int b = q >> 11, t = q & (SEQ - 1);
    const size_t arow = (size_t)q * D_MODEL + scol;
    const u16* Bg0 = wob + (size_t)(blockIdx.y * 128 + srow) * D_MODEL + scol;
    const u16* Bg1 = Bg0 + (size_t)64 * D_MODEL;
    u16* Al = Asmem + srow * 32 + scol;
    u16* Bl0 = Bsmem + srow * 32 + scol;
    u16* Bl1 = Bl0 + 64 * 32;

    for (int k0 = 0; k0 < D_MODEL; k0 += 32) {
        __syncthreads();
        // A path: fused (Po0+Po1)*rinv -> bf16 -> LDS
        int h = (k0 + scol) >> 6;
        int bhq = (b * NHEADS + h) * SEQ + t;
        float l = Ls[bhq] + Ls[32 * SEQ + bhq];
        float rinv = 1.0f / l;
        uint4 A0 = *(const uint4*)&Po0[arow + k0];
        uint4 A1 = *(const uint4*)&Po1[arow + k0];
        const u16* p0 = (const u16*)&A0;
        const u16* p1 = (const u16*)&A1;
        uint4 wv;
        u32* wvp = (u32*)&wv;
#pragma unroll
        for (int j = 0; j < 4; ++j) {
            float s0 = (bf2f(p0[2 * j]) + bf2f(p1[2 * j])) * rinv;
            float s1 = (bf2f(p0[2 * j + 1]) + bf2f(p1[2 * j + 1])) * rinv;
            wvp[j] = pack2bf(s0, s1);
        }
        *(uint4*)Al = wv;
        // B path: async as before
        async_copy16(Bg0 + k0, Bl0);
        async_copy16(Bg1 + k0, Bl1);
        __syncthreads();
        bf16x8 af[2], bfr[4];
#pragma unroll
        for (int mt = 0; mt < 2; ++mt)
            af[mt] = *(const bf16x8*)&Asmem[(waveM * 32 + mt * 16 + l16) * 32 + quad * 8];
#pragma unroll
        for (int nt = 0; nt < 4; ++nt)
            bfr[nt] = *(const bf16x8*)&Bsmem[(waveN * 64 + nt * 16 + l16) * 32 + quad * 8];
#pragma unroll
        for (int mt = 0; mt < 2; ++mt)
#pragma unroll
            for (int nt = 0; nt < 4; ++nt)
                acc[mt][nt] = __builtin_amdgcn_mfma_f32_16x16x32_bf16(af[mt], bfr[nt], acc[mt][nt], 0, 0, 0);
    }

    const int gm0 = blockIdx.x * 64 + waveM * 32 + quad * 4;
    const int gn0 = blockIdx.y * 128 + waveN * 64 + l16;

    float bvv[4];
#pragma unroll
    for (int nt = 0; nt < 4; ++nt) bvv[nt] = bo[gn0 + nt * 16];
#pragma unroll
    for (int mt = 0; mt < 2; ++mt)
#pragma unroll
        for (int nt = 0; nt < 4; ++nt)
#pragma unroll
            for (int r = 0; r < 4; ++r)
                dout[(size_t)(gm0 + mt * 16 + r) * D_MODEL + gn0 + nt * 16] = acc[mt][nt][r] + bvv[nt];
}

// ---------------- launch ----------------
extern "C" void kernel_launch(void* const* d_in, const int* in_sizes, int n_in,
                              void* d_out, int out_size, void* d_ws, size_t ws_size,
                              hipStream_t stream) {
    const float* x  = (const float*)d_in[0];
    const float* Wq = (const float*)d_in[1];
    const float* bq = (const float*)d_in[2];
    const float* Wk = (const float*)d_in[3];
    const float* bk = (const float*)d_in[4];
    const float* Wv = (const float*)d_in[5];
    const float* bv = (const float*)d_in[6];
    const float* Wo = (const float*)d_in[7];
    const float* bo = (const float*)d_in[8];
    float* dout = (float*)d_out;

    char* ws = (char*)d_ws;
    size_t off = 0;
    u16* xb  = (u16*)(ws + off); off += (size_t)BT * D_MODEL * 2;        // 8 MB; reused as Po1 by flash
    u16* wqb = (u16*)(ws + off); off += (size_t)D_MODEL * D_MODEL * 2;
    u16* wkb = (u16*)(ws + off); off += (size_t)D_MODEL * D_MODEL * 2;
    u16* wvb = (u16*)(ws + off); off += (size_t)D_MODEL * D_MODEL * 2;
    u16* wob = (u16*)(ws + off); off += (size_t)D_MODEL * D_MODEL * 2;
    u16* Qb  = (u16*)(ws + off); off += (size_t)BT * D_MODEL * 2;
    u16* Kb  = (u16*)(ws + off); off += (size_t)BT * D_MODEL * 2;
    u16* VTb = (u16*)(ws + off); off += (size_t)BT * D_MODEL * 2;
    u16* Po0 = (u16*)(ws + off); off += (size_t)BT * D_MODEL * 2;
    float* cosT = (float*)(ws + off); off += (size_t)SEQ * HDIM * 4;
    float* sinT = (float*)(ws + off); off += (size_t)SEQ * HDIM * 4;
    float* Ls   = (float*)(ws + off); off += (size_t)2 * 32 * SEQ * 4;   // 0.5 MB
    u16* Po1 = xb;  // alias: xb is dead after gemm_qkv

    const int prepN = X4 + 4 * W4 + ROPE_N;
    prep_kernel<<<dim3((prepN + 255) / 256), 256, 0, stream>>>(
        x, Wq, Wk, Wv, Wo, xb, wqb, wkb, wvb, wob, cosT, sinT);
    gemm_qkv_kernel<<<dim3(BT / 128, D_MODEL / 128, 3), 256, 0, stream>>>(
        xb, wqb, wkb, wvb, bq, bk, bv, cosT, sinT, Qb, Kb, VTb);
    flash_kernel<<<dim3(SEQ / 256, NBATCH * NHEADS, 2), 256, 0, stream>>>(
        Qb, Kb, VTb, Po0, Po1, Ls);
    gemm_out_kernel<<<dim3(BT / 64, D_MODEL / 128), 256, 0, stream>>>(
        Po0, Po1, Ls, wob, bo, dout);
}

// Round 9
// 227.404 us; speedup vs baseline: 1.0983x; 1.0983x over previous
//
#include <hip/hip_runtime.h>
#include <hip/hip_bf16.h>
#include <cstdint>

#define D_MODEL 1024
#define NHEADS 16
#define HDIM 64
#define SEQ 2048
#define NBATCH 2
#define BT (NBATCH * SEQ) /* 4096 */

typedef short bf16x8 __attribute__((ext_vector_type(8)));
typedef float f32x4 __attribute__((ext_vector_type(4)));
typedef unsigned short u16;
typedef unsigned int u32;

__device__ inline u16 f2bf(float f) {  // RNE
    union { float f; u32 u; } x;
    x.f = f;
    u32 r = (x.u + 0x7fffu + ((x.u >> 16) & 1u)) >> 16;
    return (u16)r;
}

__device__ inline u32 pack2bf(float a, float b) {  // lo=bf16(a), hi=bf16(b), RNE via HW pack
    union { __hip_bfloat162 h; u32 u; } c;
    c.h = __float22bfloat162_rn(float2{a, b});
    return c.u;
}

__device__ inline float bf2f(u16 v) {
    union { u32 u; float f; } x;
    x.u = ((u32)v) << 16;
    return x.f;
}

__device__ inline void async_copy16(const u16* g, u16* l) {
    __builtin_amdgcn_global_load_lds((const __attribute__((address_space(1))) void*)g,
                                     (__attribute__((address_space(3))) void*)l, 16, 0, 0);
}

// ---------------- prep: casts + rope cs table, one launch ----------------
#define X4 (BT * D_MODEL / 4)        /* 1048576 */
#define W4 (D_MODEL * D_MODEL / 4)   /* 262144  */
#define ROPE_N (SEQ * 32)            /* 65536: (t, dm) pairs */

__global__ void prep_kernel(const float* __restrict__ x,
                            const float* __restrict__ wq, const float* __restrict__ wk,
                            const float* __restrict__ wv, const float* __restrict__ wo,
                            u16* __restrict__ xb,
                            u16* __restrict__ dq, u16* __restrict__ dk,
                            u16* __restrict__ dv, u16* __restrict__ dow,
                            float2* __restrict__ csT) {
    int idx = blockIdx.x * blockDim.x + threadIdx.x;
    if (idx < X4) {
        float4 v = ((const float4*)x)[idx];
        ushort4 o;
        o.x = f2bf(v.x); o.y = f2bf(v.y); o.z = f2bf(v.z); o.w = f2bf(v.w);
        ((ushort4*)xb)[idx] = o;
    } else if (idx < X4 + 4 * W4) {
        int j = idx - X4;
        int w = j >> 18, i = j & (W4 - 1);
        const float* s = (w == 0) ? wq : (w == 1) ? wk : (w == 2) ? wv : wo;
        u16* d = (w == 0) ? dq : (w == 1) ? dk : (w == 2) ? dv : dow;
        float4 v = ((const float4*)s)[i];
        ushort4 o;
        o.x = f2bf(v.x); o.y = f2bf(v.y); o.z = f2bf(v.z); o.w = f2bf(v.w);
        ((ushort4*)d)[i] = o;
    } else {
        int j = idx - (X4 + 4 * W4);
        if (j < ROPE_N) {
            int t = j >> 5, dm = j & 31;
            float invf = exp2f(-(float)dm * (13.287712379549449f / 32.0f));
            float ang = (float)t * invf;
            float s, c;
            sincosf(ang, &s, &c);
            csT[t * 32 + dm] = float2{c, s};
        }
    }
}

// ---------------- m97-style GEMM core (128x128 tile) ----------------
__device__ inline void gemm_tile_core(const u16* __restrict__ A, const u16* __restrict__ Bw,
                                      int blkM, int blkN,
                                      u16* Asmem, u16* Bsmem, f32x4 acc[4][4]) {
    const int tid = threadIdx.x;
    const int lane = tid & 63;
    const int wave = tid >> 6;
    const int waveM = wave >> 1, waveN = wave & 1;
    const int quad = lane >> 4, l16 = lane & 15;

    const int srow = tid >> 2;
    const int scol = (tid & 3) << 3;
    const u16* Ag0 = A + (size_t)(blkM * 128 + srow) * D_MODEL + scol;
    const u16* Ag1 = Ag0 + (size_t)64 * D_MODEL;
    const u16* Bg0 = Bw + (size_t)(blkN * 128 + srow) * D_MODEL + scol;
    const u16* Bg1 = Bg0 + (size_t)64 * D_MODEL;
    u16* Al0 = Asmem + srow * 32 + scol;
    u16* Al1 = Al0 + 64 * 32;
    u16* Bl0 = Bsmem + srow * 32 + scol;
    u16* Bl1 = Bl0 + 64 * 32;

    for (int k0 = 0; k0 < D_MODEL; k0 += 32) {
        __syncthreads();
        async_copy16(Ag0 + k0, Al0);
        async_copy16(Ag1 + k0, Al1);
        async_copy16(Bg0 + k0, Bl0);
        async_copy16(Bg1 + k0, Bl1);
        __syncthreads();
        bf16x8 af[4], bfr[4];
#pragma unroll
        for (int mt = 0; mt < 4; ++mt)
            af[mt] = *(const bf16x8*)&Asmem[(waveM * 64 + mt * 16 + l16) * 32 + quad * 8];
#pragma unroll
        for (int nt = 0; nt < 4; ++nt)
            bfr[nt] = *(const bf16x8*)&Bsmem[(waveN * 64 + nt * 16 + l16) * 32 + quad * 8];
#pragma unroll
        for (int mt = 0; mt < 4; ++mt)
#pragma unroll
            for (int nt = 0; nt < 4; ++nt)
                acc[mt][nt] = __builtin_amdgcn_mfma_f32_16x16x32_bf16(af[mt], bfr[nt], acc[mt][nt], 0, 0, 0);
    }
}

// ---------------- fused QKV projection + bias + RoPE + layout ----------------
#define QSCALE 0.1803368801111204f /* (1/8) * log2(e) */
#define VPAD 132 /* vtile row stride in u16 */

__global__ __launch_bounds__(256) void gemm_qkv_kernel(
    const u16* __restrict__ xb,
    const u16* __restrict__ wqb, const u16* __restrict__ wkb, const u16* __restrict__ wvb,
    const float* __restrict__ bq, const float* __restrict__ bk, const float* __restrict__ bv,
    const float2* __restrict__ csT,
    u16* __restrict__ Qb, u16* __restrict__ Kb, u16* __restrict__ VTb) {
    __shared__ __align__(16) u16 smem[128 * VPAD];
    u16* Asmem = smem;
    u16* Bsmem = smem + 128 * 32;

    const int z = blockIdx.z;
    const u16* Bw = (z == 0) ? wqb : (z == 1) ? wkb : wvb;
    const float* bias = (z == 0) ? bq : (z == 1) ? bk : bv;

    f32x4 acc[4][4];
#pragma unroll
    for (int mt = 0; mt < 4; ++mt)
#pragma unroll
        for (int nt = 0; nt < 4; ++nt)
            acc[mt][nt] = (f32x4){0.f, 0.f, 0.f, 0.f};

    gemm_tile_core(xb, Bw, blockIdx.x, blockIdx.y, Asmem, Bsmem, acc);

    const int tid = threadIdx.x;
    const int lane = tid & 63, wave = tid >> 6;
    const int waveM = wave >> 1, waveN = wave & 1;
    const int quad = lane >> 4, l16 = lane & 15;
    const int gm0 = blockIdx.x * 128 + waveM * 64 + quad * 4;
    const int gn0 = blockIdx.y * 128 + waveN * 64 + l16;

    float bvv[4];
#pragma unroll
    for (int nt = 0; nt < 4; ++nt) bvv[nt] = bias[gn0 + nt * 16];
#pragma unroll
    for (int mt = 0; mt < 4; ++mt)
#pragma unroll
        for (int nt = 0; nt < 4; ++nt)
#pragma unroll
            for (int r = 0; r < 4; ++r) acc[mt][nt][r] += bvv[nt];

    if (z < 2) {
        // RoPE via complex rotation on (d, d+32) pairs; cs table shared by the pair.
        u16* dst = (z == 0) ? Qb : Kb;
        const float post = (z == 0) ? QSCALE : 1.0f;
        const int h = 2 * blockIdx.y + waveN;  // head is wave-uniform
#pragma unroll
        for (int mt = 0; mt < 4; ++mt) {
#pragma unroll
            for (int r = 0; r < 4; ++r) {
                int gm = gm0 + mt * 16 + r;
                int t = gm & (SEQ - 1), b = gm >> 11;
                float2 cs0 = csT[t * 32 + l16];        // dm = l16   (pairs nt0/nt2)
                float2 cs1 = csT[t * 32 + 16 + l16];   // dm = l16+16 (pairs nt1/nt3)
                float a0 = acc[mt][0][r], a1 = acc[mt][1][r];
                float a2 = acc[mt][2][r], a3 = acc[mt][3][r];
                size_t base = ((size_t)(b * NHEADS + h) * SEQ + t) * HDIM;
                dst[base + l16]      = f2bf((a0 * cs0.x - a2 * cs0.y) * post);
                dst[base + l16 + 16] = f2bf((a1 * cs1.x - a3 * cs1.y) * post);
                dst[base + l16 + 32] = f2bf((a2 * cs0.x + a0 * cs0.y) * post);
                dst[base + l16 + 48] = f2bf((a3 * cs1.x + a1 * cs1.y) * post);
            }
        }
    } else {
        // V epilogue: transpose through LDS, then fully-coalesced stores to VTb[bh][d][t]
        __syncthreads();
#pragma unroll
        for (int mt = 0; mt < 4; ++mt) {
            int t_local = waveM * 64 + mt * 16 + quad * 4;
#pragma unroll
            for (int nt = 0; nt < 4; ++nt) {
                int n_local = waveN * 64 + nt * 16 + l16;
                uint2 w;
                w.x = pack2bf(acc[mt][nt][0], acc[mt][nt][1]);
                w.y = pack2bf(acc[mt][nt][2], acc[mt][nt][3]);
                *(uint2*)&smem[n_local * VPAD + t_local] = w;
            }
        }
        __syncthreads();
        const int row = tid >> 1;
        const int hc = (tid & 1) * 64;
        const int n_g = blockIdx.y * 128 + row;
        const int h = n_g >> 6, d = n_g & 63;
        const int b = (blockIdx.x * 128) >> 11;
        const int t0 = ((blockIdx.x * 128) & (SEQ - 1)) + hc;
        u16* dst = &VTb[((size_t)(b * NHEADS + h) * HDIM + d) * SEQ + t0];
        const u16* src = &smem[row * VPAD + hc];
#pragma unroll
        for (int j = 0; j < 8; ++j)
            *(int4*)&dst[j * 8] = *(const int4*)&src[j * 8];
    }
}

// ---------------- flash attention: R7 structure + swizzled Ps (50 KB LDS) + kt-split N ----
// grid: x = 8 (q tiles of 256), y = 32 (bh), z = nsplit. block = 256 = 4 waves, 64 q/wave.
#define LPAD 72  /* Ks/VTs row stride in u16 */

__global__ __launch_bounds__(256, 1) void flash_kernel(
    const u16* __restrict__ Qb, const u16* __restrict__ Kb, const u16* __restrict__ VTb,
    u16* __restrict__ Po0, u16* __restrict__ Po1, u16* __restrict__ Po2, u16* __restrict__ Po3,
    float* __restrict__ Ls, int iters) {
    __shared__ __align__(16) u16 Ks[64 * LPAD];    // [kk][d]  9.2 KB
    __shared__ __align__(16) u16 VTs[64 * LPAD];   // [d][kk]  9.2 KB
    __shared__ __align__(16) u16 Ps[4][64 * 64];   // per-wave [q][kk], XOR-swizzled chunks, 32.8 KB

    const int tid = threadIdx.x;
    const int wave = tid >> 6, lane = tid & 63;
    const int quad = lane >> 4, l16 = lane & 15;
    const int sw = l16 & 7;  // Ps chunk swizzle key (row-determined)
    const int bh = blockIdx.y;
    const int hf = blockIdx.z;
    const u16* Qh = Qb + (size_t)bh * SEQ * HDIM;
    const u16* Kh = Kb + (size_t)bh * SEQ * HDIM;
    const u16* Vh = VTb + (size_t)bh * HDIM * SEQ;
    const int qblk = blockIdx.x * 256 + wave * 64;
    u16* Pw = (u16*)Ps[wave];

    // Q B-frags (Q pre-scaled by 0.125*log2e): aq[nt2][ks], 64 q rows
    bf16x8 aq[4][2];
#pragma unroll
    for (int nt2 = 0; nt2 < 4; ++nt2)
#pragma unroll
        for (int ks = 0; ks < 2; ++ks)
            aq[nt2][ks] = *(const bf16x8*)&Qh[(qblk + nt2 * 16 + l16) * HDIM + ks * 32 + quad * 8];

    f32x4 o[4][4];
    float lsum[4] = {0.f, 0.f, 0.f, 0.f};
#pragma unroll
    for (int mt2 = 0; mt2 < 4; ++mt2)
#pragma unroll
        for (int nt = 0; nt < 4; ++nt) o[mt2][nt] = (f32x4){0.f, 0.f, 0.f, 0.f};

    const int lr = tid >> 2;         // 0..63
    const int lc = (tid & 3) * 16;   // u16 col: 0,16,32,48

    const int kt0 = hf * iters;
    for (int kt = kt0; kt < kt0 + iters; ++kt) {
        __syncthreads();
        *(int4*)&Ks[lr * LPAD + lc] = *(const int4*)&Kh[(kt * 64 + lr) * HDIM + lc];
        *(int4*)&Ks[lr * LPAD + lc + 8] = *(const int4*)&Kh[(kt * 64 + lr) * HDIM + lc + 8];
        *(int4*)&VTs[lr * LPAD + lc] = *(const int4*)&Vh[lr * SEQ + kt * 64 + lc];
        *(int4*)&VTs[lr * LPAD + lc + 8] = *(const int4*)&Vh[lr * SEQ + kt * 64 + lc + 8];
        __syncthreads();

        // S^T[kk][q] = K·Q^T : per wave 64kk x 64q. C/D: col(l16)=q, row(quad*4+r)=kk
        f32x4 sacc[4][4];
#pragma unroll
        for (int mt = 0; mt < 4; ++mt)
#pragma unroll
            for (int nt2 = 0; nt2 < 4; ++nt2) sacc[mt][nt2] = (f32x4){0.f, 0.f, 0.f, 0.f};
#pragma unroll
        for (int ks = 0; ks < 2; ++ks) {
            bf16x8 kf[4];
#pragma unroll
            for (int mt = 0; mt < 4; ++mt)
                kf[mt] = *(const bf16x8*)&Ks[(mt * 16 + l16) * LPAD + ks * 32 + quad * 8];
#pragma unroll
            for (int mt = 0; mt < 4; ++mt)
#pragma unroll
                for (int nt2 = 0; nt2 < 4; ++nt2)
                    sacc[mt][nt2] = __builtin_amdgcn_mfma_f32_16x16x32_bf16(kf[mt], aq[nt2][ks], sacc[mt][nt2], 0, 0, 0);
        }

        // P = exp2(S); b64 write into swizzled chunk; in-lane partial rowsum
#pragma unroll
        for (int mt = 0; mt < 4; ++mt) {
#pragma unroll
            for (int nt2 = 0; nt2 < 4; ++nt2) {
                float p0 = __builtin_amdgcn_exp2f(sacc[mt][nt2][0]);
                float p1 = __builtin_amdgcn_exp2f(sacc[mt][nt2][1]);
                float p2 = __builtin_amdgcn_exp2f(sacc[mt][nt2][2]);
                float p3 = __builtin_amdgcn_exp2f(sacc[mt][nt2][3]);
                lsum[nt2] += (p0 + p1) + (p2 + p3);
                uint2 w;
                w.x = pack2bf(p0, p1);
                w.y = pack2bf(p2, p3);
                int chunk = (mt * 2 + (quad >> 1)) ^ sw;   // 8-u16 chunk, swizzled by row
                *(uint2*)&Pw[(nt2 * 16 + l16) * 64 + chunk * 8 + (quad & 1) * 4] = w;
            }
        }
        // no barrier: Ps slice is private to this wave; DS ops are wave-ordered

        // O += P·V : A=P[q][kk] frags (swizzled chunks), B=V[d][kk] frags
#pragma unroll
        for (int ks = 0; ks < 2; ++ks) {
            bf16x8 pf[4], vf[4];
#pragma unroll
            for (int mt2 = 0; mt2 < 4; ++mt2) {
                int chunk = (ks * 4 + quad) ^ sw;
                pf[mt2] = *(const bf16x8*)&Pw[(mt2 * 16 + l16) * 64 + chunk * 8];
            }
#pragma unroll
            for (int nt = 0; nt < 4; ++nt)
                vf[nt] = *(const bf16x8*)&VTs[(nt * 16 + l16) * LPAD + ks * 32 + quad * 8];
#pragma unroll
            for (int mt2 = 0; mt2 < 4; ++mt2)
#pragma unroll
                for (int nt = 0; nt < 4; ++nt)
                    o[mt2][nt] = __builtin_amdgcn_mfma_f32_16x16x32_bf16(pf[mt2], vf[nt], o[mt2][nt], 0, 0, 0);
        }
    }

    // complete row sums over the 4 quads (disjoint kk)
#pragma unroll
    for (int nt2 = 0; nt2 < 4; ++nt2) {
        lsum[nt2] += __shfl_xor(lsum[nt2], 16, 64);
        lsum[nt2] += __shfl_xor(lsum[nt2], 32, 64);
    }

    // epilogue: UNNORMALIZED partial O (bf16) + row sums; gemm_out normalizes.
    const int b = bh >> 4, h = bh & 15;
    u16* dst = (hf == 0) ? Po0 : (hf == 1) ? Po1 : (hf == 2) ? Po2 : Po3;
#pragma unroll
    for (int mt2 = 0; mt2 < 4; ++mt2) {
#pragma unroll
        for (int nt = 0; nt < 4; ++nt) {
            int d = nt * 16 + l16;
#pragma unroll
            for (int r = 0; r < 4; ++r) {
                int q = qblk + mt2 * 16 + quad * 4 + r;
                dst[((size_t)(b * SEQ + q)) * D_MODEL + h * HDIM + d] = f2bf(o[mt2][nt][r]);
            }
        }
    }
    if (quad == 0) {
#pragma unroll
        for (int nt2 = 0; nt2 < 4; ++nt2) {
            int q = qblk + nt2 * 16 + l16;
            Ls[hf * (32 * SEQ) + bh * SEQ + q] = lsum[nt2];
        }
    }
}

// ---------------- output projection: fused combine (Σ Po_s * rinv) in A-staging ----------
__global__ __launch_bounds__(256) void gemm_out_kernel(
    const u16* __restrict__ Po0, const u16* __restrict__ Po1,
    const u16* __restrict__ Po2, const u16* __restrict__ Po3,
    const float* __restrict__ Ls, int nsplit,
    const u16* __restrict__ wob, const float* __restrict__ bo, float* __restrict__ dout) {
    __shared__ __align__(16) u16 Asmem[64 * 32];
    __shared__ __align__(16) u16 Bsmem[128 * 32];

    const int tid = threadIdx.x;
    const int lane = tid & 63, wave = tid >> 6;
    const int waveM = wave >> 1, waveN = wave & 1;
    const int quad = lane >> 4, l16 = lane & 15;

    f32x4 acc[2][4];
#pragma unroll
    for (int mt = 0; mt < 2; ++mt)
#pragma unroll
        for (int nt = 0; nt < 4; ++nt) acc[mt][nt] = (f32x4){0.f, 0.f, 0.f, 0.f};

    const int srow = tid >> 2;
    const int scol = (tid & 3) << 3;
    const int q = blockIdx.x * 64 + srow;
    const int b = q >> 11, t = q & (SEQ - 1);
    const size_t arow = (size_t)q * D_MODEL + scol;
    const u16* Bg0 = wob + (size_t)(blockIdx.y * 128 + srow) * D_MODEL + scol;
    const u16* Bg1 = Bg0 + (size_t)64 * D_MODEL;
    u16* Al = Asmem + srow * 32 + scol;
    u16* Bl0 = Bsmem + srow * 32 + scol;
    u16* Bl1 = Bl0 + 64 * 32;

    for (int k0 = 0; k0 < D_MODEL; k0 += 32) {
        __syncthreads();
        // A path: fused (Σ partials)*rinv -> bf16 -> LDS
        int h = (k0 + scol) >> 6;
        int bhq = (b * NHEADS + h) * SEQ + t;
        float l = Ls[bhq] + Ls[32 * SEQ + bhq];
        if (nsplit == 4) l += Ls[2 * 32 * SEQ + bhq] + Ls[3 * 32 * SEQ + bhq];
        float rinv = 1.0f / l;
        uint4 A0 = *(const uint4*)&Po0[arow + k0];
        uint4 A1 = *(const uint4*)&Po1[arow + k0];
        const u16* p0 = (const u16*)&A0;
        const u16* p1 = (const u16*)&A1;
        float sv[8];
#pragma unroll
        for (int e = 0; e < 8; ++e) sv[e] = bf2f(p0[e]) + bf2f(p1[e]);
        if (nsplit == 4) {
            uint4 A2 = *(const uint4*)&Po2[arow + k0];
            uint4 A3 = *(const uint4*)&Po3[arow + k0];
            const u16* p2 = (const u16*)&A2;
            const u16* p3 = (const u16*)&A3;
#pragma unroll
            for (int e = 0; e < 8; ++e) sv[e] += bf2f(p2[e]) + bf2f(p3[e]);
        }
        uint4 wv;
        u32* wvp = (u32*)&wv;
#pragma unroll
        for (int j = 0; j < 4; ++j)
            wvp[j] = pack2bf(sv[2 * j] * rinv, sv[2 * j + 1] * rinv);
        *(uint4*)Al = wv;
        // B path: async as before
        async_copy16(Bg0 + k0, Bl0);
        async_copy16(Bg1 + k0, Bl1);
        __syncthreads();
        bf16x8 af[2], bfr[4];
#pragma unroll
        for (int mt = 0; mt < 2; ++mt)
            af[mt] = *(const bf16x8*)&Asmem[(waveM * 32 + mt * 16 + l16) * 32 + quad * 8];
#pragma unroll
        for (int nt = 0; nt < 4; ++nt)
            bfr[nt] = *(const bf16x8*)&Bsmem[(waveN * 64 + nt * 16 + l16) * 32 + quad * 8];
#pragma unroll
        for (int mt = 0; mt < 2; ++mt)
#pragma unroll
            for (int nt = 0; nt < 4; ++nt)
                acc[mt][nt] = __builtin_amdgcn_mfma_f32_16x16x32_bf16(af[mt], bfr[nt], acc[mt][nt], 0, 0, 0);
    }

    const int gm0 = blockIdx.x * 64 + waveM * 32 + quad * 4;
    const int gn0 = blockIdx.y * 128 + waveN * 64 + l16;

    float bvv[4];
#pragma unroll
    for (int nt = 0; nt < 4; ++nt) bvv[nt] = bo[gn0 + nt * 16];
#pragma unroll
    for (int mt = 0; mt < 2; ++mt)
#pragma unroll
        for (int nt = 0; nt < 4; ++nt)
#pragma unroll
            for (int r = 0; r < 4; ++r)
                dout[(size_t)(gm0 + mt * 16 + r) * D_MODEL + gn0 + nt * 16] = acc[mt][nt][r] + bvv[nt];
}

// ---------------- launch ----------------
extern "C" void kernel_launch(void* const* d_in, const int* in_sizes, int n_in,
                              void* d_out, int out_size, void* d_ws, size_t ws_size,
                              hipStream_t stream) {
    const float* x  = (const float*)d_in[0];
    const float* Wq = (const float*)d_in[1];
    const float* bq = (const float*)d_in[2];
    const float* Wk = (const float*)d_in[3];
    const float* bk = (const float*)d_in[4];
    const float* Wv = (const float*)d_in[5];
    const float* bv = (const float*)d_in[6];
    const float* Wo = (const float*)d_in[7];
    const float* bo = (const float*)d_in[8];
    float* dout = (float*)d_out;

    char* ws = (char*)d_ws;
    size_t off = 0;
    u16* xb  = (u16*)(ws + off); off += (size_t)BT * D_MODEL * 2;        // 8 MB; reused as Po1
    u16* wqb = (u16*)(ws + off); off += (size_t)D_MODEL * D_MODEL * 2;
    u16* wkb = (u16*)(ws + off); off += (size_t)D_MODEL * D_MODEL * 2;
    u16* wvb = (u16*)(ws + off); off += (size_t)D_MODEL * D_MODEL * 2;
    u16* wob = (u16*)(ws + off); off += (size_t)D_MODEL * D_MODEL * 2;
    u16* Qb  = (u16*)(ws + off); off += (size_t)BT * D_MODEL * 2;
    u16* Kb  = (u16*)(ws + off); off += (size_t)BT * D_MODEL * 2;
    u16* VTb = (u16*)(ws + off); off += (size_t)BT * D_MODEL * 2;
    u16* Po0 = (u16*)(ws + off); off += (size_t)BT * D_MODEL * 2;
    float2* csT = (float2*)(ws + off); off += (size_t)SEQ * 32 * 8;      // 0.5 MB
    float* Ls   = (float*)(ws + off); off += (size_t)4 * 32 * SEQ * 4;   // 1 MB
    u16* Po1 = xb;  // alias: xb is dead after gemm_qkv
    // optional extra partials for kt-split 4:
    u16* Po2 = (u16*)(ws + off); size_t off4 = off + (size_t)BT * D_MODEL * 2;
    u16* Po3 = (u16*)(ws + off4); off4 += (size_t)BT * D_MODEL * 2;
    const int nsplit = (ws_size >= off4) ? 4 : 2;
    if (nsplit == 2) { Po2 = Po0; Po3 = Po1; }  // unused when nsplit==2

    const int prepN = X4 + 4 * W4 + ROPE_N;
    prep_kernel<<<dim3((prepN + 255) / 256), 256, 0, stream>>>(
        x, Wq, Wk, Wv, Wo, xb, wqb, wkb, wvb, wob, csT);
    gemm_qkv_kernel<<<dim3(BT / 128, D_MODEL / 128, 3), 256, 0, stream>>>(
        xb, wqb, wkb, wvb, bq, bk, bv, csT, Qb, Kb, VTb);
    flash_kernel<<<dim3(SEQ / 256, NBATCH * NHEADS, nsplit), 256, 0, stream>>>(
        Qb, Kb, VTb, Po0, Po1, Po2, Po3, Ls, 32 / nsplit);
    gemm_out_kernel<<<dim3(BT / 64, D_MODEL / 128), 256, 0, stream>>>(
        Po0, Po1, Po2, Po3, Ls, nsplit, wob, bo, dout);
}

// Round 10
// 207.559 us; speedup vs baseline: 1.2033x; 1.0956x over previous
//
#include <hip/hip_runtime.h>
#include <hip/hip_bf16.h>
#include <cstdint>

#define D_MODEL 1024
#define NHEADS 16
#define HDIM 64
#define SEQ 2048
#define NBATCH 2
#define BT (NBATCH * SEQ) /* 4096 */

typedef short bf16x8 __attribute__((ext_vector_type(8)));
typedef float f32x4 __attribute__((ext_vector_type(4)));
typedef unsigned short u16;
typedef unsigned int u32;

__device__ inline u16 f2bf(float f) {  // RNE
    union { float f; u32 u; } x;
    x.f = f;
    u32 r = (x.u + 0x7fffu + ((x.u >> 16) & 1u)) >> 16;
    return (u16)r;
}

__device__ inline u32 pack2bf(float a, float b) {  // lo=bf16(a), hi=bf16(b), RNE via HW pack
    union { __hip_bfloat162 h; u32 u; } c;
    c.h = __float22bfloat162_rn(float2{a, b});
    return c.u;
}

__device__ inline float bf2f(u16 v) {
    union { u32 u; float f; } x;
    x.u = ((u32)v) << 16;
    return x.f;
}

__device__ inline void async_copy16(const u16* g, u16* l) {
    __builtin_amdgcn_global_load_lds((const __attribute__((address_space(1))) void*)g,
                                     (__attribute__((address_space(3))) void*)l, 16, 0, 0);
}

// ---------------- prep: casts + rope cs table, one launch ----------------
#define X4 (BT * D_MODEL / 4)        /* 1048576 */
#define W4 (D_MODEL * D_MODEL / 4)   /* 262144  */
#define ROPE_N (SEQ * 32)            /* 65536: (t, dm) pairs */

__global__ void prep_kernel(const float* __restrict__ x,
                            const float* __restrict__ wq, const float* __restrict__ wk,
                            const float* __restrict__ wv, const float* __restrict__ wo,
                            u16* __restrict__ xb,
                            u16* __restrict__ dq, u16* __restrict__ dk,
                            u16* __restrict__ dv, u16* __restrict__ dow,
                            float2* __restrict__ csT) {
    int idx = blockIdx.x * blockDim.x + threadIdx.x;
    if (idx < X4) {
        float4 v = ((const float4*)x)[idx];
        ushort4 o;
        o.x = f2bf(v.x); o.y = f2bf(v.y); o.z = f2bf(v.z); o.w = f2bf(v.w);
        ((ushort4*)xb)[idx] = o;
    } else if (idx < X4 + 4 * W4) {
        int j = idx - X4;
        int w = j >> 18, i = j & (W4 - 1);
        const float* s = (w == 0) ? wq : (w == 1) ? wk : (w == 2) ? wv : wo;
        u16* d = (w == 0) ? dq : (w == 1) ? dk : (w == 2) ? dv : dow;
        float4 v = ((const float4*)s)[i];
        ushort4 o;
        o.x = f2bf(v.x); o.y = f2bf(v.y); o.z = f2bf(v.z); o.w = f2bf(v.w);
        ((ushort4*)d)[i] = o;
    } else {
        int j = idx - (X4 + 4 * W4);
        if (j < ROPE_N) {
            int t = j >> 5, dm = j & 31;
            float invf = exp2f(-(float)dm * (13.287712379549449f / 32.0f));
            float ang = (float)t * invf;
            float s, c;
            sincosf(ang, &s, &c);
            csT[t * 32 + dm] = float2{c, s};
        }
    }
}

// ---------------- m97-style GEMM core (128x128 tile) ----------------
__device__ inline void gemm_tile_core(const u16* __restrict__ A, const u16* __restrict__ Bw,
                                      int blkM, int blkN,
                                      u16* Asmem, u16* Bsmem, f32x4 acc[4][4]) {
    const int tid = threadIdx.x;
    const int lane = tid & 63;
    const int wave = tid >> 6;
    const int waveM = wave >> 1, waveN = wave & 1;
    const int quad = lane >> 4, l16 = lane & 15;

    const int srow = tid >> 2;
    const int scol = (tid & 3) << 3;
    const u16* Ag0 = A + (size_t)(blkM * 128 + srow) * D_MODEL + scol;
    const u16* Ag1 = Ag0 + (size_t)64 * D_MODEL;
    const u16* Bg0 = Bw + (size_t)(blkN * 128 + srow) * D_MODEL + scol;
    const u16* Bg1 = Bg0 + (size_t)64 * D_MODEL;
    u16* Al0 = Asmem + srow * 32 + scol;
    u16* Al1 = Al0 + 64 * 32;
    u16* Bl0 = Bsmem + srow * 32 + scol;
    u16* Bl1 = Bl0 + 64 * 32;

    for (int k0 = 0; k0 < D_MODEL; k0 += 32) {
        __syncthreads();
        async_copy16(Ag0 + k0, Al0);
        async_copy16(Ag1 + k0, Al1);
        async_copy16(Bg0 + k0, Bl0);
        async_copy16(Bg1 + k0, Bl1);
        __syncthreads();
        bf16x8 af[4], bfr[4];
#pragma unroll
        for (int mt = 0; mt < 4; ++mt)
            af[mt] = *(const bf16x8*)&Asmem[(waveM * 64 + mt * 16 + l16) * 32 + quad * 8];
#pragma unroll
        for (int nt = 0; nt < 4; ++nt)
            bfr[nt] = *(const bf16x8*)&Bsmem[(waveN * 64 + nt * 16 + l16) * 32 + quad * 8];
#pragma unroll
        for (int mt = 0; mt < 4; ++mt)
#pragma unroll
            for (int nt = 0; nt < 4; ++nt)
                acc[mt][nt] = __builtin_amdgcn_mfma_f32_16x16x32_bf16(af[mt], bfr[nt], acc[mt][nt], 0, 0, 0);
    }
}

// ---------------- fused QKV projection + bias + RoPE + layout ----------------
#define QSCALE 0.1803368801111204f /* (1/8) * log2(e) */
#define VPAD 132 /* vtile row stride in u16 */

__global__ __launch_bounds__(256) void gemm_qkv_kernel(
    const u16* __restrict__ xb,
    const u16* __restrict__ wqb, const u16* __restrict__ wkb, const u16* __restrict__ wvb,
    const float* __restrict__ bq, const float* __restrict__ bk, const float* __restrict__ bv,
    const float2* __restrict__ csT,
    u16* __restrict__ Qb, u16* __restrict__ Kb, u16* __restrict__ VTb) {
    __shared__ __align__(16) u16 smem[128 * VPAD];
    u16* Asmem = smem;
    u16* Bsmem = smem + 128 * 32;

    const int z = blockIdx.z;
    const u16* Bw = (z == 0) ? wqb : (z == 1) ? wkb : wvb;
    const float* bias = (z == 0) ? bq : (z == 1) ? bk : bv;

    f32x4 acc[4][4];
#pragma unroll
    for (int mt = 0; mt < 4; ++mt)
#pragma unroll
        for (int nt = 0; nt < 4; ++nt)
            acc[mt][nt] = (f32x4){0.f, 0.f, 0.f, 0.f};

    gemm_tile_core(xb, Bw, blockIdx.x, blockIdx.y, Asmem, Bsmem, acc);

    const int tid = threadIdx.x;
    const int lane = tid & 63, wave = tid >> 6;
    const int waveM = wave >> 1, waveN = wave & 1;
    const int quad = lane >> 4, l16 = lane & 15;
    const int gm0 = blockIdx.x * 128 + waveM * 64 + quad * 4;
    const int gn0 = blockIdx.y * 128 + waveN * 64 + l16;

    float bvv[4];
#pragma unroll
    for (int nt = 0; nt < 4; ++nt) bvv[nt] = bias[gn0 + nt * 16];
#pragma unroll
    for (int mt = 0; mt < 4; ++mt)
#pragma unroll
        for (int nt = 0; nt < 4; ++nt)
#pragma unroll
            for (int r = 0; r < 4; ++r) acc[mt][nt][r] += bvv[nt];

    if (z < 2) {
        // RoPE via complex rotation on (d, d+32) pairs; cs table shared by the pair.
        u16* dst = (z == 0) ? Qb : Kb;
        const float post = (z == 0) ? QSCALE : 1.0f;
        const int h = 2 * blockIdx.y + waveN;  // head is wave-uniform
#pragma unroll
        for (int mt = 0; mt < 4; ++mt) {
#pragma unroll
            for (int r = 0; r < 4; ++r) {
                int gm = gm0 + mt * 16 + r;
                int t = gm & (SEQ - 1), b = gm >> 11;
                float2 cs0 = csT[t * 32 + l16];        // dm = l16   (pairs nt0/nt2)
                float2 cs1 = csT[t * 32 + 16 + l16];   // dm = l16+16 (pairs nt1/nt3)
                float a0 = acc[mt][0][r], a1 = acc[mt][1][r];
                float a2 = acc[mt][2][r], a3 = acc[mt][3][r];
                size_t base = ((size_t)(b * NHEADS + h) * SEQ + t) * HDIM;
                dst[base + l16]      = f2bf((a0 * cs0.x - a2 * cs0.y) * post);
                dst[base + l16 + 16] = f2bf((a1 * cs1.x - a3 * cs1.y) * post);
                dst[base + l16 + 32] = f2bf((a2 * cs0.x + a0 * cs0.y) * post);
                dst[base + l16 + 48] = f2bf((a3 * cs1.x + a1 * cs1.y) * post);
            }
        }
    } else {
        // V epilogue: transpose through LDS, then fully-coalesced stores to VTb[bh][d][t]
        __syncthreads();
#pragma unroll
        for (int mt = 0; mt < 4; ++mt) {
            int t_local = waveM * 64 + mt * 16 + quad * 4;
#pragma unroll
            for (int nt = 0; nt < 4; ++nt) {
                int n_local = waveN * 64 + nt * 16 + l16;
                uint2 w;
                w.x = pack2bf(acc[mt][nt][0], acc[mt][nt][1]);
                w.y = pack2bf(acc[mt][nt][2], acc[mt][nt][3]);
                *(uint2*)&smem[n_local * VPAD + t_local] = w;
            }
        }
        __syncthreads();
        const int row = tid >> 1;
        const int hc = (tid & 1) * 64;
        const int n_g = blockIdx.y * 128 + row;
        const int h = n_g >> 6, d = n_g & 63;
        const int b = (blockIdx.x * 128) >> 11;
        const int t0 = ((blockIdx.x * 128) & (SEQ - 1)) + hc;
        u16* dst = &VTb[((size_t)(b * NHEADS + h) * HDIM + d) * SEQ + t0];
        const u16* src = &smem[row * VPAD + hc];
#pragma unroll
        for (int j = 0; j < 8; ++j)
            *(int4*)&dst[j * 8] = *(const int4*)&src[j * 8];
    }
}

// ---------------- flash attention: R7 structure (LDS K/V, 64 q/wave, kt-split 2) ----------
#define LPAD 72  /* row stride in u16 */

__global__ __launch_bounds__(256, 1) void flash_kernel(
    const u16* __restrict__ Qb, const u16* __restrict__ Kb, const u16* __restrict__ VTb,
    u16* __restrict__ Po0, u16* __restrict__ Po1, float* __restrict__ Ls) {
    __shared__ __align__(16) u16 Ks[64 * LPAD];     // [kk][d]  9.2 KB
    __shared__ __align__(16) u16 VTs[64 * LPAD];    // [d][kk]  9.2 KB
    __shared__ __align__(16) u16 Ps[4][64 * LPAD];  // per-wave [q][kk]  36.9 KB

    const int tid = threadIdx.x;
    const int wave = tid >> 6, lane = tid & 63;
    const int quad = lane >> 4, l16 = lane & 15;
    const int bh = blockIdx.y;
    const int hf = blockIdx.z;
    const u16* Qh = Qb + (size_t)bh * SEQ * HDIM;
    const u16* Kh = Kb + (size_t)bh * SEQ * HDIM;
    const u16* Vh = VTb + (size_t)bh * HDIM * SEQ;
    const int qblk = blockIdx.x * 256 + wave * 64;
    u16* Pw = (u16*)Ps[wave];

    // Q B-frags (Q pre-scaled by 0.125*log2e): aq[nt2][ks], 64 q rows
    bf16x8 aq[4][2];
#pragma unroll
    for (int nt2 = 0; nt2 < 4; ++nt2)
#pragma unroll
        for (int ks = 0; ks < 2; ++ks)
            aq[nt2][ks] = *(const bf16x8*)&Qh[(qblk + nt2 * 16 + l16) * HDIM + ks * 32 + quad * 8];

    f32x4 o[4][4];
    float lsum[4] = {0.f, 0.f, 0.f, 0.f};
#pragma unroll
    for (int mt2 = 0; mt2 < 4; ++mt2)
#pragma unroll
        for (int nt = 0; nt < 4; ++nt) o[mt2][nt] = (f32x4){0.f, 0.f, 0.f, 0.f};

    const int lr = tid >> 2;         // 0..63
    const int lc = (tid & 3) * 16;   // u16 col: 0,16,32,48

    const int ktEnd = (hf + 1) * (SEQ / 128);
    for (int kt = hf * (SEQ / 128); kt < ktEnd; ++kt) {
        __syncthreads();
        *(int4*)&Ks[lr * LPAD + lc] = *(const int4*)&Kh[(kt * 64 + lr) * HDIM + lc];
        *(int4*)&Ks[lr * LPAD + lc + 8] = *(const int4*)&Kh[(kt * 64 + lr) * HDIM + lc + 8];
        *(int4*)&VTs[lr * LPAD + lc] = *(const int4*)&Vh[lr * SEQ + kt * 64 + lc];
        *(int4*)&VTs[lr * LPAD + lc + 8] = *(const int4*)&Vh[lr * SEQ + kt * 64 + lc + 8];
        __syncthreads();

        // S^T[kk][q] = K·Q^T : per wave 64kk x 64q. C/D: col(l16)=q, row(quad*4+r)=kk
        f32x4 sacc[4][4];
#pragma unroll
        for (int mt = 0; mt < 4; ++mt)
#pragma unroll
            for (int nt2 = 0; nt2 < 4; ++nt2) sacc[mt][nt2] = (f32x4){0.f, 0.f, 0.f, 0.f};
#pragma unroll
        for (int ks = 0; ks < 2; ++ks) {
            bf16x8 kf[4];
#pragma unroll
            for (int mt = 0; mt < 4; ++mt)
                kf[mt] = *(const bf16x8*)&Ks[(mt * 16 + l16) * LPAD + ks * 32 + quad * 8];
#pragma unroll
            for (int mt = 0; mt < 4; ++mt)
#pragma unroll
                for (int nt2 = 0; nt2 < 4; ++nt2)
                    sacc[mt][nt2] = __builtin_amdgcn_mfma_f32_16x16x32_bf16(kf[mt], aq[nt2][ks], sacc[mt][nt2], 0, 0, 0);
        }

        // P = exp2(S); lane holds 4 contiguous kk per (mt,nt2) -> b64 write; in-lane partial rowsum
#pragma unroll
        for (int mt = 0; mt < 4; ++mt) {
#pragma unroll
            for (int nt2 = 0; nt2 < 4; ++nt2) {
                float p0 = __builtin_amdgcn_exp2f(sacc[mt][nt2][0]);
                float p1 = __builtin_amdgcn_exp2f(sacc[mt][nt2][1]);
                float p2 = __builtin_amdgcn_exp2f(sacc[mt][nt2][2]);
                float p3 = __builtin_amdgcn_exp2f(sacc[mt][nt2][3]);
                lsum[nt2] += (p0 + p1) + (p2 + p3);
                uint2 w;
                w.x = pack2bf(p0, p1);
                w.y = pack2bf(p2, p3);
                *(uint2*)&Pw[(nt2 * 16 + l16) * LPAD + mt * 16 + quad * 4] = w;
            }
        }
        // no barrier: Ps slice is private to this wave; DS ops are wave-ordered

        // O += P·V : A=P[q][kk] frags, B=V[d][kk] frags
#pragma unroll
        for (int ks = 0; ks < 2; ++ks) {
            bf16x8 pf[4], vf[4];
#pragma unroll
            for (int mt2 = 0; mt2 < 4; ++mt2)
                pf[mt2] = *(const bf16x8*)&Pw[(mt2 * 16 + l16) * LPAD + ks * 32 + quad * 8];
#pragma unroll
            for (int nt = 0; nt < 4; ++nt)
                vf[nt] = *(const bf16x8*)&VTs[(nt * 16 + l16) * LPAD + ks * 32 + quad * 8];
#pragma unroll
            for (int mt2 = 0; mt2 < 4; ++mt2)
#pragma unroll
                for (int nt = 0; nt < 4; ++nt)
                    o[mt2][nt] = __builtin_amdgcn_mfma_f32_16x16x32_bf16(pf[mt2], vf[nt], o[mt2][nt], 0, 0, 0);
        }
    }

    // complete row sums over the 4 quads (disjoint kk): lane l16 then holds q = nt2*16+l16
#pragma unroll
    for (int nt2 = 0; nt2 < 4; ++nt2) {
        lsum[nt2] += __shfl_xor(lsum[nt2], 16, 64);
        lsum[nt2] += __shfl_xor(lsum[nt2], 32, 64);
    }

    // epilogue: write UNNORMALIZED partial O (bf16) + row sums; gemm_out normalizes.
    const int b = bh >> 4, h = bh & 15;
    u16* dst = hf ? Po1 : Po0;
#pragma unroll
    for (int mt2 = 0; mt2 < 4; ++mt2) {
#pragma unroll
        for (int nt = 0; nt < 4; ++nt) {
            int d = nt * 16 + l16;
#pragma unroll
            for (int r = 0; r < 4; ++r) {
                int q = qblk + mt2 * 16 + quad * 4 + r;
                dst[((size_t)(b * SEQ + q)) * D_MODEL + h * HDIM + d] = f2bf(o[mt2][nt][r]);
            }
        }
    }
    if (quad == 0) {
#pragma unroll
        for (int nt2 = 0; nt2 < 4; ++nt2) {
            int q = qblk + nt2 * 16 + l16;
            Ls[hf * (32 * SEQ) + bh * SEQ + q] = lsum[nt2];
        }
    }
}

// ---------------- output projection: fused combine, software-pipelined A loads ----------
__global__ __launch_bounds__(256) void gemm_out_kernel(
    const u16* __restrict__ Po0, const u16* __restrict__ Po1, const float* __restrict__ Ls,
    const u16* __restrict__ wob, const float* __restrict__ bo, float* __restrict__ dout) {
    __shared__ __align__(16) u16 Asmem[64 * 32];
    __shared__ __align__(16) u16 Bsmem[128 * 32];

    const int tid = threadIdx.x;
    const int lane = tid & 63, wave = tid >> 6;
    const int waveM = wave >> 1, waveN = wave & 1;
    const int quad = lane >> 4, l16 = lane & 15;

    f32x4 acc[2][4];
#pragma unroll
    for (int mt = 0; mt < 2; ++mt)
#pragma unroll
        for (int nt = 0; nt < 4; ++nt) acc[mt][nt] = (f32x4){0.f, 0.f, 0.f, 0.f};

    const int srow = tid >> 2;
    const int scol = (tid & 3) << 3;
    const int q = blockIdx.x * 64 + srow;
    const int b = q >> 11, t = q & (SEQ - 1);
    const size_t arow = (size_t)q * D_MODEL + scol;
    const u16* Bg0 = wob + (size_t)(blockIdx.y * 128 + srow) * D_MODEL + scol;
    const u16* Bg1 = Bg0 + (size_t)64 * D_MODEL;
    u16* Al = Asmem + srow * 32 + scol;
    u16* Bl0 = Bsmem + srow * 32 + scol;
    u16* Bl1 = Bl0 + 64 * 32;

    // precompute 1/l per head for this thread's row (used 2 iters each)
    float rinvh[NHEADS];
    {
        const int bhq0 = b * NHEADS * SEQ + t;
#pragma unroll
        for (int h = 0; h < NHEADS; ++h) {
            int bhq = bhq0 + h * SEQ;
            rinvh[h] = 1.0f / (Ls[bhq] + Ls[32 * SEQ + bhq]);
        }
    }

    // prefetch iter 0's A rows
    uint4 A0 = *(const uint4*)&Po0[arow];
    uint4 A1 = *(const uint4*)&Po1[arow];

    for (int k0 = 0; k0 < D_MODEL; k0 += 32) {
        __syncthreads();
        // A path: fused (Po0+Po1)*rinv -> bf16 -> LDS (uses prefetched regs)
        float rinv = rinvh[(k0 + scol) >> 6];
        const u16* p0 = (const u16*)&A0;
        const u16* p1 = (const u16*)&A1;
        uint4 wv;
        u32* wvp = (u32*)&wv;
#pragma unroll
        for (int j = 0; j < 4; ++j) {
            float s0 = (bf2f(p0[2 * j]) + bf2f(p1[2 * j])) * rinv;
            float s1 = (bf2f(p0[2 * j + 1]) + bf2f(p1[2 * j + 1])) * rinv;
            wvp[j] = pack2bf(s0, s1);
        }
        *(uint4*)Al = wv;
        // B path: async global->LDS
        async_copy16(Bg0 + k0, Bl0);
        async_copy16(Bg1 + k0, Bl1);
        // prefetch next iter's A rows; latency drains with the barrier's vmcnt wait
        if (k0 + 32 < D_MODEL) {
            A0 = *(const uint4*)&Po0[arow + k0 + 32];
            A1 = *(const uint4*)&Po1[arow + k0 + 32];
        }
        __syncthreads();
        bf16x8 af[2], bfr[4];
#pragma unroll
        for (int mt = 0; mt < 2; ++mt)
            af[mt] = *(const bf16x8*)&Asmem[(waveM * 32 + mt * 16 + l16) * 32 + quad * 8];
#pragma unroll
        for (int nt = 0; nt < 4; ++nt)
            bfr[nt] = *(const bf16x8*)&Bsmem[(waveN * 64 + nt * 16 + l16) * 32 + quad * 8];
#pragma unroll
        for (int mt = 0; mt < 2; ++mt)
#pragma unroll
            for (int nt = 0; nt < 4; ++nt)
                acc[mt][nt] = __builtin_amdgcn_mfma_f32_16x16x32_bf16(af[mt], bfr[nt], acc[mt][nt], 0, 0, 0);
    }

    const int gm0 = blockIdx.x * 64 + waveM * 32 + quad * 4;
    const int gn0 = blockIdx.y * 128 + waveN * 64 + l16;

    float bvv[4];
#pragma unroll
    for (int nt = 0; nt < 4; ++nt) bvv[nt] = bo[gn0 + nt * 16];
#pragma unroll
    for (int mt = 0; mt < 2; ++mt)
#pragma unroll
        for (int nt = 0; nt < 4; ++nt)
#pragma unroll
            for (int r = 0; r < 4; ++r)
                dout[(size_t)(gm0 + mt * 16 + r) * D_MODEL + gn0 + nt * 16] = acc[mt][nt][r] + bvv[nt];
}

// ---------------- launch ----------------
extern "C" void kernel_launch(void* const* d_in, const int* in_sizes, int n_in,
                              void* d_out, int out_size, void* d_ws, size_t ws_size,
                              hipStream_t stream) {
    const float* x  = (const float*)d_in[0];
    const float* Wq = (const float*)d_in[1];
    const float* bq = (const float*)d_in[2];
    const float* Wk = (const float*)d_in[3];
    const float* bk = (const float*)d_in[4];
    const float* Wv = (const float*)d_in[5];
    const float* bv = (const float*)d_in[6];
    const float* Wo = (const float*)d_in[7];
    const float* bo = (const float*)d_in[8];
    float* dout = (float*)d_out;

    char* ws = (char*)d_ws;
    size_t off = 0;
    u16* xb  = (u16*)(ws + off); off += (size_t)BT * D_MODEL * 2;        // 8 MB; reused as Po1
    u16* wqb = (u16*)(ws + off); off += (size_t)D_MODEL * D_MODEL * 2;
    u16* wkb = (u16*)(ws + off); off += (size_t)D_MODEL * D_MODEL * 2;
    u16* wvb = (u16*)(ws + off); off += (size_t)D_MODEL * D_MODEL * 2;
    u16* wob = (u16*)(ws + off); off += (size_t)D_MODEL * D_MODEL * 2;
    u16* Qb  = (u16*)(ws + off); off += (size_t)BT * D_MODEL * 2;
    u16* Kb  = (u16*)(ws + off); off += (size_t)BT * D_MODEL * 2;
    u16* VTb = (u16*)(ws + off); off += (size_t)BT * D_MODEL * 2;
    u16* Po0 = (u16*)(ws + off); off += (size_t)BT * D_MODEL * 2;
    float2* csT = (float2*)(ws + off); off += (size_t)SEQ * 32 * 8;      // 0.5 MB
    float* Ls   = (float*)(ws + off); off += (size_t)2 * 32 * SEQ * 4;   // 0.5 MB
    u16* Po1 = xb;  // alias: xb is dead after gemm_qkv

    const int prepN = X4 + 4 * W4 + ROPE_N;
    prep_kernel<<<dim3((prepN + 255) / 256), 256, 0, stream>>>(
        x, Wq, Wk, Wv, Wo, xb, wqb, wkb, wvb, wob, csT);
    gemm_qkv_kernel<<<dim3(BT / 128, D_MODEL / 128, 3), 256, 0, stream>>>(
        xb, wqb, wkb, wvb, bq, bk, bv, csT, Qb, Kb, VTb);
    flash_kernel<<<dim3(SEQ / 256, NBATCH * NHEADS, 2), 256, 0, stream>>>(
        Qb, Kb, VTb, Po0, Po1, Ls);
    gemm_out_kernel<<<dim3(BT / 64, D_MODEL / 128), 256, 0, stream>>>(
        Po0, Po1, Ls, wob, bo, dout);
}